// Round 1
// baseline (3550.302 us; speedup 1.0000x reference)
//
#include <hip/hip_runtime.h>

#define EPSV 1e-5f
#define TILE 64
#define BK 16
#define LDSP 68   // padded LDS row: float4-aligned (68=4*17), breaks 2^n bank stride

// ---------------------------------------------------------------------------
// NN GEMM + BatchNorm + ReLU epilogue.
// Wt: [M][K] row-major (weights, shared across batch)
// X:  [K][N] row-major, batched via strideX (blockIdx.z)
// Y:  [M][N] row-major, batched via strideY
// Y[o][n] = relu(inv[o]*(sum_k Wt[o][k]*X[k][n]) + beta[o])
// ---------------------------------------------------------------------------
__global__ __launch_bounds__(256)
void gemm_nn_cbr(const float* __restrict__ Wt, const float* __restrict__ X,
                 const float* __restrict__ gg, const float* __restrict__ bb,
                 const float* __restrict__ mm, const float* __restrict__ vv,
                 float* __restrict__ Y,
                 int M, int K, int N, long strideX, long strideY)
{
    __shared__ float As[BK][LDSP];
    __shared__ float Bs[BK][LDSP];
    const int tid = threadIdx.x;
    const int n0 = blockIdx.x * TILE;
    const int o0 = blockIdx.y * TILE;
    const float* Xb = X + (long)blockIdx.z * strideX;
    float* Yb = Y + (long)blockIdx.z * strideY;

    const int tx = tid & 15;
    const int ty = tid >> 4;

    // A tile load (transpose into As[k][o]): thread -> (o, 4 consecutive k)
    const int a_o = tid >> 2;          // 0..63
    const int a_k = (tid & 3) << 2;    // 0,4,8,12
    // B tile load (direct Bs[k][n]): thread -> (k row, 4 consecutive n)
    const int b_r = tid >> 4;          // 0..15
    const int b_c = (tid & 15) << 2;   // 0..60

    float acc[4][4] = {};

    for (int k0 = 0; k0 < K; k0 += BK) {
        float4 av = *(const float4*)&Wt[(long)(o0 + a_o) * K + k0 + a_k];
        float4 bv = *(const float4*)&Xb[(long)(k0 + b_r) * N + n0 + b_c];
        __syncthreads();
        As[a_k + 0][a_o] = av.x;
        As[a_k + 1][a_o] = av.y;
        As[a_k + 2][a_o] = av.z;
        As[a_k + 3][a_o] = av.w;
        *(float4*)&Bs[b_r][b_c] = bv;
        __syncthreads();
        #pragma unroll
        for (int kk = 0; kk < BK; ++kk) {
            float4 a = *(const float4*)&As[kk][ty << 2];
            float4 b = *(const float4*)&Bs[kk][tx << 2];
            acc[0][0] += a.x * b.x; acc[0][1] += a.x * b.y; acc[0][2] += a.x * b.z; acc[0][3] += a.x * b.w;
            acc[1][0] += a.y * b.x; acc[1][1] += a.y * b.y; acc[1][2] += a.y * b.z; acc[1][3] += a.y * b.w;
            acc[2][0] += a.z * b.x; acc[2][1] += a.z * b.y; acc[2][2] += a.z * b.z; acc[2][3] += a.z * b.w;
            acc[3][0] += a.w * b.x; acc[3][1] += a.w * b.y; acc[3][2] += a.w * b.z; acc[3][3] += a.w * b.w;
        }
    }

    #pragma unroll
    for (int ii = 0; ii < 4; ++ii) {
        const int o = o0 + (ty << 2) + ii;
        const float inv  = gg[o] * rsqrtf(vv[o] + EPSV);
        const float beta = bb[o] - mm[o] * inv;
        float4 r;
        r.x = fmaxf(acc[ii][0] * inv + beta, 0.0f);
        r.y = fmaxf(acc[ii][1] * inv + beta, 0.0f);
        r.z = fmaxf(acc[ii][2] * inv + beta, 0.0f);
        r.w = fmaxf(acc[ii][3] * inv + beta, 0.0f);
        *(float4*)&Yb[(long)o * N + n0 + (tx << 2)] = r;
    }
}

// ---------------------------------------------------------------------------
// TN GEMM (attention logits), one batch.
// A = q[b]: [512][4096] (channel-major), B = k[b]: [512][4096]
// attn[i][j] = sum_c A[c][i] * B[c][j]    (i=query pos, j=key pos)
// ---------------------------------------------------------------------------
__global__ __launch_bounds__(256)
void gemm_tn_logits(const float* __restrict__ A, const float* __restrict__ B,
                    float* __restrict__ attn)
{
    __shared__ float As[BK][LDSP];
    __shared__ float Bs[BK][LDSP];
    const int tid = threadIdx.x;
    const int j0 = blockIdx.x * TILE;   // key tile
    const int i0 = blockIdx.y * TILE;   // query tile
    const int tx = tid & 15;
    const int ty = tid >> 4;

    const int l_r = tid >> 4;          // k-row 0..15
    const int l_c = (tid & 15) << 2;   // col 0..60

    float acc[4][4] = {};

    for (int k0 = 0; k0 < 512; k0 += BK) {
        float4 av = *(const float4*)&A[(long)(k0 + l_r) * 4096 + i0 + l_c];
        float4 bv = *(const float4*)&B[(long)(k0 + l_r) * 4096 + j0 + l_c];
        __syncthreads();
        *(float4*)&As[l_r][l_c] = av;
        *(float4*)&Bs[l_r][l_c] = bv;
        __syncthreads();
        #pragma unroll
        for (int kk = 0; kk < BK; ++kk) {
            float4 a = *(const float4*)&As[kk][ty << 2];
            float4 b = *(const float4*)&Bs[kk][tx << 2];
            acc[0][0] += a.x * b.x; acc[0][1] += a.x * b.y; acc[0][2] += a.x * b.z; acc[0][3] += a.x * b.w;
            acc[1][0] += a.y * b.x; acc[1][1] += a.y * b.y; acc[1][2] += a.y * b.z; acc[1][3] += a.y * b.w;
            acc[2][0] += a.z * b.x; acc[2][1] += a.z * b.y; acc[2][2] += a.z * b.z; acc[2][3] += a.z * b.w;
            acc[3][0] += a.w * b.x; acc[3][1] += a.w * b.y; acc[3][2] += a.w * b.z; acc[3][3] += a.w * b.w;
        }
    }

    #pragma unroll
    for (int ii = 0; ii < 4; ++ii) {
        const int i = i0 + (ty << 2) + ii;
        *(float4*)&attn[(long)i * 4096 + j0 + (tx << 2)] =
            make_float4(acc[ii][0], acc[ii][1], acc[ii][2], acc[ii][3]);
    }
}

// ---------------------------------------------------------------------------
// Row softmax over attn [4096][4096], one row per block.
// ---------------------------------------------------------------------------
__global__ __launch_bounds__(256)
void softmax_rows(float* __restrict__ attn)
{
    __shared__ float buf[4096];
    __shared__ float red[256];
    float* p = attn + (long)blockIdx.x * 4096;
    const int tid = threadIdx.x;

    float lmax = -3.4e38f;
    for (int i = tid; i < 4096; i += 256) {
        float x = p[i];
        buf[i] = x;
        lmax = fmaxf(lmax, x);
    }
    red[tid] = lmax;
    __syncthreads();
    for (int s = 128; s > 0; s >>= 1) {
        if (tid < s) red[tid] = fmaxf(red[tid], red[tid + s]);
        __syncthreads();
    }
    const float mx = red[0];
    __syncthreads();

    float lsum = 0.0f;
    for (int i = tid; i < 4096; i += 256) {
        float e = __expf(buf[i] - mx);
        buf[i] = e;
        lsum += e;
    }
    red[tid] = lsum;
    __syncthreads();
    for (int s = 128; s > 0; s >>= 1) {
        if (tid < s) red[tid] += red[tid + s];
        __syncthreads();
    }
    const float inv = 1.0f / red[0];
    __syncthreads();

    for (int i = tid; i < 4096; i += 256) p[i] = buf[i] * inv;
}

// ---------------------------------------------------------------------------
// NT GEMM (attention update), one batch, accumulated TRANSPOSED and fused +f:
// f[c][n] += sum_m V[c][m] * attn[n][m]     (in-place update of f[b])
// V = v[b]: [512][4096], attn: [4096][4096]
// ---------------------------------------------------------------------------
__global__ __launch_bounds__(256)
void gemm_nt_addf(const float* __restrict__ V, const float* __restrict__ attn,
                  float* __restrict__ f)
{
    __shared__ float As[BK][LDSP];
    __shared__ float Bs[BK][LDSP];
    const int tid = threadIdx.x;
    const int n0 = blockIdx.x * TILE;   // spatial-pos tile (output cols)
    const int c0 = blockIdx.y * TILE;   // channel tile (output rows)
    const int tx = tid & 15;
    const int ty = tid >> 4;

    // both operands are K-contiguous (K = m); transpose-load both
    const int a_o = tid >> 2;          // 0..63 (row within tile)
    const int a_k = (tid & 3) << 2;    // 0,4,8,12 (k offset)

    float acc[4][4] = {};

    for (int k0 = 0; k0 < 4096; k0 += BK) {
        float4 av = *(const float4*)&V[(long)(c0 + a_o) * 4096 + k0 + a_k];
        float4 bv = *(const float4*)&attn[(long)(n0 + a_o) * 4096 + k0 + a_k];
        __syncthreads();
        As[a_k + 0][a_o] = av.x;
        As[a_k + 1][a_o] = av.y;
        As[a_k + 2][a_o] = av.z;
        As[a_k + 3][a_o] = av.w;
        Bs[a_k + 0][a_o] = bv.x;
        Bs[a_k + 1][a_o] = bv.y;
        Bs[a_k + 2][a_o] = bv.z;
        Bs[a_k + 3][a_o] = bv.w;
        __syncthreads();
        #pragma unroll
        for (int kk = 0; kk < BK; ++kk) {
            float4 a = *(const float4*)&As[kk][ty << 2];
            float4 b = *(const float4*)&Bs[kk][tx << 2];
            acc[0][0] += a.x * b.x; acc[0][1] += a.x * b.y; acc[0][2] += a.x * b.z; acc[0][3] += a.x * b.w;
            acc[1][0] += a.y * b.x; acc[1][1] += a.y * b.y; acc[1][2] += a.y * b.z; acc[1][3] += a.y * b.w;
            acc[2][0] += a.z * b.x; acc[2][1] += a.z * b.y; acc[2][2] += a.z * b.z; acc[2][3] += a.z * b.w;
            acc[3][0] += a.w * b.x; acc[3][1] += a.w * b.y; acc[3][2] += a.w * b.z; acc[3][3] += a.w * b.w;
        }
    }

    #pragma unroll
    for (int ii = 0; ii < 4; ++ii) {
        const int c = c0 + (ty << 2) + ii;
        float* dst = &f[(long)c * 4096 + n0 + (tx << 2)];
        float4 old = *(const float4*)dst;
        old.x += acc[ii][0];
        old.y += acc[ii][1];
        old.z += acc[ii][2];
        old.w += acc[ii][3];
        *(float4*)dst = old;
    }
}

// ---------------------------------------------------------------------------
extern "C" void kernel_launch(void* const* d_in, const int* in_sizes, int n_in,
                              void* d_out, int out_size, void* d_ws, size_t ws_size,
                              hipStream_t stream)
{
    (void)in_sizes; (void)n_in; (void)out_size; (void)ws_size;
    constexpr int B = 4, C = 2048, R = 512, N = 4096;

    const float* feature = (const float*)d_in[0];
    const float* rW = (const float*)d_in[1];
    const float* rg = (const float*)d_in[2];
    const float* rb = (const float*)d_in[3];
    const float* rm = (const float*)d_in[4];
    const float* rv = (const float*)d_in[5];
    const float* qW = (const float*)d_in[6];
    const float* qg = (const float*)d_in[7];
    const float* qb = (const float*)d_in[8];
    const float* qm = (const float*)d_in[9];
    const float* qv = (const float*)d_in[10];
    const float* kW = (const float*)d_in[11];
    const float* kg = (const float*)d_in[12];
    const float* kb = (const float*)d_in[13];
    const float* km = (const float*)d_in[14];
    const float* kv = (const float*)d_in[15];
    const float* vW = (const float*)d_in[16];
    const float* vg = (const float*)d_in[17];
    const float* vb = (const float*)d_in[18];
    const float* vm = (const float*)d_in[19];
    const float* vv = (const float*)d_in[20];
    const float* uW = (const float*)d_in[21];
    const float* ug = (const float*)d_in[22];
    const float* ub = (const float*)d_in[23];
    const float* um = (const float*)d_in[24];
    const float* uv = (const float*)d_in[25];

    const size_t fsz = (size_t)B * R * N;            // 8,388,608 floats
    float* f    = (float*)d_ws;
    float* q_   = f  + fsz;
    float* k_   = q_ + fsz;
    float* v_   = k_ + fsz;
    float* attn = v_ + fsz;                          // N*N floats, reused per batch

    float* out = (float*)d_out;
    const dim3 blk(256);

    // f = CBR(feature, r)   [B,512,4096]
    gemm_nn_cbr<<<dim3(N / TILE, R / TILE, B), blk, 0, stream>>>(
        rW, feature, rg, rb, rm, rv, f, R, C, N, (long)C * N, (long)R * N);

    // q,k,v = CBR(f, {q,k,v})
    gemm_nn_cbr<<<dim3(N / TILE, R / TILE, B), blk, 0, stream>>>(
        qW, f, qg, qb, qm, qv, q_, R, R, N, (long)R * N, (long)R * N);
    gemm_nn_cbr<<<dim3(N / TILE, R / TILE, B), blk, 0, stream>>>(
        kW, f, kg, kb, km, kv, k_, R, R, N, (long)R * N, (long)R * N);
    gemm_nn_cbr<<<dim3(N / TILE, R / TILE, B), blk, 0, stream>>>(
        vW, f, vg, vb, vm, vv, v_, R, R, N, (long)R * N, (long)R * N);

    // attention, batch-sequential through the shared attn buffer
    for (int b = 0; b < B; ++b) {
        const float* qb_ = q_ + (size_t)b * R * N;
        const float* kb_ = k_ + (size_t)b * R * N;
        const float* vb_ = v_ + (size_t)b * R * N;
        float* fb_ = f + (size_t)b * R * N;

        gemm_tn_logits<<<dim3(N / TILE, N / TILE), blk, 0, stream>>>(qb_, kb_, attn);
        softmax_rows<<<dim3(N), blk, 0, stream>>>(attn);
        gemm_nt_addf<<<dim3(N / TILE, R / TILE), blk, 0, stream>>>(vb_, attn, fb_);
    }

    // out = CBR(f + upd, u)   [B,2048,4096]
    gemm_nn_cbr<<<dim3(N / TILE, C / TILE, B), blk, 0, stream>>>(
        uW, f, ug, ub, um, uv, out, C, R, N, (long)R * N, (long)C * N);
}

// Round 3
// 1060.687 us; speedup vs baseline: 3.3472x; 3.3472x over previous
//
#include <hip/hip_runtime.h>

#define EPSV 1e-5f

typedef unsigned short u16;
typedef __attribute__((ext_vector_type(8))) _Float16 half8;
typedef __attribute__((ext_vector_type(4))) float floatx4;

__device__ __forceinline__ float h2f(u16 h) {
    return (float)__builtin_bit_cast(_Float16, h);
}
__device__ __forceinline__ u16 f2h(float f) {
    _Float16 h = (_Float16)f;
    return __builtin_bit_cast(u16, h);
}

// ---------------------------------------------------------------------------
// NT fp16 MFMA GEMM: D[i][j] = sum_k A[i][k] * B[j][k]
// A: [I][ldA] fp16 (K contiguous), B: [J][ldB] fp16 (K contiguous)
// Tile 128x128, BK=32, 256 threads (4 waves, each a 64x64 quadrant, 16 MFMAs).
// Staging via global_load_lds width=16 (m97 structure).
// MODE: 0 = plain (fp32 out), 1 = BN+ReLU per col j, 2 = BN+ReLU per row i,
//       3 = add fp16 tensor `addf` (same layout as out)
// ---------------------------------------------------------------------------
template <int MODE, typename OUTT>
__global__ __launch_bounds__(256)
void gemm_nt(const u16* __restrict__ A, const u16* __restrict__ B,
             OUTT* __restrict__ C_,
             const float* __restrict__ inv_, const float* __restrict__ beta_,
             const u16* __restrict__ addf,
             int K, int ldA, int ldB, int ldC,
             long strideA, long strideB, long strideC)
{
    __shared__ u16 As[128 * 32];
    __shared__ u16 Bs[128 * 32];

    const int tid = threadIdx.x;
    const int w = tid >> 6;        // wave 0..3
    const int l = tid & 63;        // lane
    const int j0 = blockIdx.x * 128;
    const int i0 = blockIdx.y * 128;

    const u16* Ab = A + (long)blockIdx.z * strideA;
    const u16* Bb = B + (long)blockIdx.z * strideB;

    // staging: per issue, wave w covers 16 rows (lane/4), granule (lane&3)*8 elems
    const int srow = w * 16 + (l >> 2);   // 0..63 (+64 for second issue)
    const int skel = (l & 3) * 8;         // k element offset

    // compute mapping: wave quadrant
    const int i_base = (w >> 1) * 64;
    const int j_base = (w & 1) * 64;
    const int lm = l & 15;
    const int kq = l >> 4;                // 0..3

    floatx4 acc[4][4];
    #pragma unroll
    for (int a = 0; a < 4; ++a)
        #pragma unroll
        for (int b = 0; b < 4; ++b) acc[a][b] = (floatx4)(0.0f);

    for (int k0 = 0; k0 < K; k0 += 32) {
        const u16* ga0 = Ab + (long)(i0 + srow) * ldA + k0 + skel;
        const u16* ga1 = Ab + (long)(i0 + 64 + srow) * ldA + k0 + skel;
        const u16* gb0 = Bb + (long)(j0 + srow) * ldB + k0 + skel;
        const u16* gb1 = Bb + (long)(j0 + 64 + srow) * ldB + k0 + skel;
        char* la0 = (char*)As + w * 1024;
        char* la1 = (char*)As + 4096 + w * 1024;
        char* lb0 = (char*)Bs + w * 1024;
        char* lb1 = (char*)Bs + 4096 + w * 1024;
        __builtin_amdgcn_global_load_lds(
            (const __attribute__((address_space(1))) unsigned int*)(const void*)ga0,
            (__attribute__((address_space(3))) unsigned int*)(void*)la0, 16, 0, 0);
        __builtin_amdgcn_global_load_lds(
            (const __attribute__((address_space(1))) unsigned int*)(const void*)ga1,
            (__attribute__((address_space(3))) unsigned int*)(void*)la1, 16, 0, 0);
        __builtin_amdgcn_global_load_lds(
            (const __attribute__((address_space(1))) unsigned int*)(const void*)gb0,
            (__attribute__((address_space(3))) unsigned int*)(void*)lb0, 16, 0, 0);
        __builtin_amdgcn_global_load_lds(
            (const __attribute__((address_space(1))) unsigned int*)(const void*)gb1,
            (__attribute__((address_space(3))) unsigned int*)(void*)lb1, 16, 0, 0);
        __syncthreads();

        half8 af[4], bf[4];
        #pragma unroll
        for (int t = 0; t < 4; ++t) {
            af[t] = *(const half8*)&As[(i_base + t * 16 + lm) * 32 + kq * 8];
            bf[t] = *(const half8*)&Bs[(j_base + t * 16 + lm) * 32 + kq * 8];
        }
        #pragma unroll
        for (int ti = 0; ti < 4; ++ti)
            #pragma unroll
            for (int tj = 0; tj < 4; ++tj)
                acc[ti][tj] = __builtin_amdgcn_mfma_f32_16x16x32_f16(
                    af[ti], bf[tj], acc[ti][tj], 0, 0, 0);
        __syncthreads();
    }

    OUTT* Cb = C_ + (long)blockIdx.z * strideC;
    #pragma unroll
    for (int ti = 0; ti < 4; ++ti) {
        #pragma unroll
        for (int tj = 0; tj < 4; ++tj) {
            const int jj = j0 + j_base + tj * 16 + lm;
            float cinv = 0.f, cbeta = 0.f;
            if (MODE == 1) { cinv = inv_[jj]; cbeta = beta_[jj]; }
            #pragma unroll
            for (int r = 0; r < 4; ++r) {
                const int ii = i0 + i_base + ti * 16 + kq * 4 + r;
                float val = acc[ti][tj][r];
                if (MODE == 1) val = fmaxf(val * cinv + cbeta, 0.0f);
                if (MODE == 2) {
                    float iv = inv_[ii], bt = beta_[ii];
                    val = fmaxf(val * iv + bt, 0.0f);
                }
                if (MODE == 3) val += h2f(addf[(long)ii * ldC + jj]);
                if (sizeof(OUTT) == 4) {
                    ((float*)Cb)[(long)ii * ldC + jj] = val;
                } else {
                    ((u16*)Cb)[(long)ii * ldC + jj] = f2h(val);
                }
            }
        }
    }
}

// ---------------------------------------------------------------------------
// weight fp32 -> fp16 + precompute BN inv/beta
// ---------------------------------------------------------------------------
__global__ __launch_bounds__(256)
void conv_weight(const float* __restrict__ W, const float* __restrict__ g,
                 const float* __restrict__ b, const float* __restrict__ m,
                 const float* __restrict__ v,
                 u16* __restrict__ Wb, float* __restrict__ inv_,
                 float* __restrict__ beta_, int cout, long n)
{
    for (long idx = (long)blockIdx.x * 256 + threadIdx.x; idx < n;
         idx += (long)gridDim.x * 256)
        Wb[idx] = f2h(W[idx]);
    int c = blockIdx.x * 256 + threadIdx.x;
    if (c < cout) {
        float iv = g[c] * rsqrtf(v[c] + EPSV);
        inv_[c] = iv;
        beta_[c] = b[c] - m[c] * iv;
    }
}

// ---------------------------------------------------------------------------
// feature [C][N] fp32 -> featT [N][C] fp16 (32x32 tiled transpose), per batch z
// ---------------------------------------------------------------------------
__global__ __launch_bounds__(256)
void transpose_conv(const float* __restrict__ in, u16* __restrict__ out,
                    int C, int N)
{
    __shared__ float t[32][33];
    const int n0 = blockIdx.x * 32, c0 = blockIdx.y * 32;
    const float* inb = in + (long)blockIdx.z * C * N;
    u16* outb = out + (long)blockIdx.z * C * N;
    const int tx = threadIdx.x & 31, ty = threadIdx.x >> 5;  // 32 x 8
    #pragma unroll
    for (int rr = 0; rr < 32; rr += 8)
        t[ty + rr][tx] = inb[(long)(c0 + ty + rr) * N + n0 + tx];
    __syncthreads();
    #pragma unroll
    for (int rr = 0; rr < 32; rr += 8)
        outb[(long)(n0 + ty + rr) * C + c0 + tx] = f2h(t[tx][ty + rr]);
}

// ---------------------------------------------------------------------------
// Row softmax on S fp32 [4096][4096]; writes fp16 result in-place over the
// first half of each row's own storage (row pitch stays 16384 B -> ld 8192 u16)
// ---------------------------------------------------------------------------
__global__ __launch_bounds__(256)
void softmax_f16(float* __restrict__ S)
{
    __shared__ float buf[4096];
    __shared__ float red[256];
    float* p = S + (long)blockIdx.x * 4096;
    u16* o = (u16*)p;
    const int tid = threadIdx.x;

    float lmax = -3.4e38f;
    for (int i = tid; i < 4096; i += 256) {
        float x = p[i];
        buf[i] = x;
        lmax = fmaxf(lmax, x);
    }
    red[tid] = lmax;
    __syncthreads();
    for (int s = 128; s > 0; s >>= 1) {
        if (tid < s) red[tid] = fmaxf(red[tid], red[tid + s]);
        __syncthreads();
    }
    const float mx = red[0];
    __syncthreads();

    float lsum = 0.0f;
    for (int i = tid; i < 4096; i += 256) {
        float e = __expf(buf[i] - mx);
        buf[i] = e;
        lsum += e;
    }
    red[tid] = lsum;
    __syncthreads();
    for (int s = 128; s > 0; s >>= 1) {
        if (tid < s) red[tid] += red[tid + s];
        __syncthreads();
    }
    const float invs = 1.0f / red[0];
    __syncthreads();

    for (int i = tid; i < 4096; i += 256) o[i] = f2h(buf[i] * invs);
}

// ---------------------------------------------------------------------------
extern "C" void kernel_launch(void* const* d_in, const int* in_sizes, int n_in,
                              void* d_out, int out_size, void* d_ws, size_t ws_size,
                              hipStream_t stream)
{
    (void)in_sizes; (void)n_in; (void)out_size; (void)ws_size;
    constexpr int B = 4, C = 2048, R = 512, N = 4096;
    constexpr long NR = (long)N * R;   // 2,097,152
    constexpr long NC = (long)N * C;   // 8,388,608

    const float* feature = (const float*)d_in[0];
    const float* W_[5]  = {(const float*)d_in[1],  (const float*)d_in[6],
                           (const float*)d_in[11], (const float*)d_in[16],
                           (const float*)d_in[21]};
    const float* G_[5]  = {(const float*)d_in[2],  (const float*)d_in[7],
                           (const float*)d_in[12], (const float*)d_in[17],
                           (const float*)d_in[22]};
    const float* Bb_[5] = {(const float*)d_in[3],  (const float*)d_in[8],
                           (const float*)d_in[13], (const float*)d_in[18],
                           (const float*)d_in[23]};
    const float* M_[5]  = {(const float*)d_in[4],  (const float*)d_in[9],
                           (const float*)d_in[14], (const float*)d_in[19],
                           (const float*)d_in[24]};
    const float* V_[5]  = {(const float*)d_in[5],  (const float*)d_in[10],
                           (const float*)d_in[15], (const float*)d_in[20],
                           (const float*)d_in[25]};
    const int cout_[5] = {R, R, R, R, C};
    const int cin_[5]  = {C, R, R, R, R};

    // ---- workspace layout (bytes) ----
    char* base = (char*)d_ws;
    size_t off = 0;
    // region0: featT fp16 [B][N][C] (64 MB) -- later reused as S fp32 [4096][4096]
    u16*   featT = (u16*)(base + off);
    float* S     = (float*)(base + off);               off += (size_t)B * NC * 2;
    u16* fT = (u16*)(base + off);                      off += (size_t)B * NR * 2;
    u16* qT = (u16*)(base + off);                      off += (size_t)B * NR * 2;
    u16* kT = (u16*)(base + off);                      off += (size_t)B * NR * 2;
    u16* vC = (u16*)(base + off);                      off += (size_t)B * NR * 2;
    u16* gT = (u16*)(base + off);                      off += (size_t)B * NR * 2;
    u16* Wb_[5]; float* inv_[5]; float* beta_[5];
    for (int i = 0; i < 5; ++i) {
        Wb_[i] = (u16*)(base + off);  off += (size_t)cout_[i] * cin_[i] * 2;
        off = (off + 255) & ~(size_t)255;
    }
    for (int i = 0; i < 5; ++i) {
        inv_[i]  = (float*)(base + off);  off += 8192;
        beta_[i] = (float*)(base + off);  off += 8192;
    }

    float* out = (float*)d_out;
    const dim3 blk(256);

    // ---- weight conversion + BN param precompute ----
    for (int i = 0; i < 5; ++i)
        conv_weight<<<512, blk, 0, stream>>>(W_[i], G_[i], Bb_[i], M_[i], V_[i],
                                             Wb_[i], inv_[i], beta_[i],
                                             cout_[i], (long)cout_[i] * cin_[i]);

    // ---- feature transpose+convert: [B][C][N] f32 -> [B][N][C] fp16 ----
    transpose_conv<<<dim3(N / 32, C / 32, B), blk, 0, stream>>>(feature, featT, C, N);

    // ---- f = CBR(feature, r): out fT [B][N][R] fp16 ----
    gemm_nt<1, u16><<<dim3(R / 128, N / 128, B), blk, 0, stream>>>(
        featT, Wb_[0], fT, inv_[0], beta_[0], nullptr,
        C, C, C, R, NC, 0, NR);

    // ---- q,k = CBR(f): [B][N][R] fp16 ----
    gemm_nt<1, u16><<<dim3(R / 128, N / 128, B), blk, 0, stream>>>(
        fT, Wb_[1], qT, inv_[1], beta_[1], nullptr,
        R, R, R, R, NR, 0, NR);
    gemm_nt<1, u16><<<dim3(R / 128, N / 128, B), blk, 0, stream>>>(
        fT, Wb_[2], kT, inv_[2], beta_[2], nullptr,
        R, R, R, R, NR, 0, NR);
    // ---- v = CBR(f), channel-major: vC [B][R][N] fp16 ----
    gemm_nt<2, u16><<<dim3(N / 128, R / 128, B), blk, 0, stream>>>(
        Wb_[3], fT, vC, inv_[3], beta_[3], nullptr,
        R, R, R, N, 0, NR, NR);

    // ---- attention, batch-serial through shared S buffer (aliases featT) ----
    for (int b = 0; b < B; ++b) {
        const u16* qb = qT + (size_t)b * NR;
        const u16* kb = kT + (size_t)b * NR;
        const u16* vb = vC + (size_t)b * NR;
        const u16* fb = fT + (size_t)b * NR;
        u16* gb = gT + (size_t)b * NR;

        // S[i][m] = sum_r q[i][r] * k[m][r]   (fp32)
        gemm_nt<0, float><<<dim3(N / 128, N / 128, 1), blk, 0, stream>>>(
            qb, kb, S, nullptr, nullptr, nullptr,
            R, R, R, N, 0, 0, 0);
        // softmax rows, write fp16 in place (row pitch 8192 u16)
        softmax_f16<<<dim3(N), blk, 0, stream>>>(S);
        // gT[n][c] = f[n][c] + sum_m P[n][m] * vC[c][m]
        gemm_nt<3, u16><<<dim3(R / 128, N / 128, 1), blk, 0, stream>>>(
            (const u16*)S, vb, gb, nullptr, nullptr, fb,
            N, 2 * N, N, R, 0, 0, 0);
    }

    // ---- out = CBR(f + upd, u): [B][C][N] fp32 ----
    gemm_nt<2, float><<<dim3(N / 128, C / 128, B), blk, 0, stream>>>(
        Wb_[4], gT, out, inv_[4], beta_[4], nullptr,
        R, R, R, N, 0, NR, NC);
}

// Round 4
// 968.301 us; speedup vs baseline: 3.6665x; 1.0954x over previous
//
#include <hip/hip_runtime.h>

#define EPSV 1e-5f

typedef unsigned short u16;
typedef __attribute__((ext_vector_type(8))) _Float16 half8;
typedef __attribute__((ext_vector_type(4))) float floatx4;

__device__ __forceinline__ float h2f(u16 h) {
    return (float)__builtin_bit_cast(_Float16, h);
}
__device__ __forceinline__ u16 f2h(float f) {
    _Float16 h = (_Float16)f;
    return __builtin_bit_cast(u16, h);
}

// ---------------------------------------------------------------------------
// NT fp16 MFMA GEMM: D[i][j] = sum_k A[i][k] * B[j][k]
// A: [I][ldA] fp16 (K contiguous), B: [J][ldB] fp16 (K contiguous)
// Tile 128x128, BK=32, 256 threads (4 waves, each a 64x64 quadrant, 16 MFMAs).
// Staging via global_load_lds width=16 (m97 structure).
// MODE: 0 = plain (fp32 out), 1 = BN+ReLU per col j, 2 = BN+ReLU per row i,
//       3 = add fp16 tensor `addf`, 4 = split-K fp32 partial into strided pool
//       (pool chunk = upper 8KB of each 16KB span; L = ((z*4096+ii)*512+jj)*4)
// ---------------------------------------------------------------------------
template <int MODE, typename OUTT>
__global__ __launch_bounds__(256)
void gemm_nt(const u16* __restrict__ A, const u16* __restrict__ B,
             OUTT* __restrict__ C_,
             const float* __restrict__ inv_, const float* __restrict__ beta_,
             const u16* __restrict__ addf,
             int K, int ldA, int ldB, int ldC,
             long strideA, long strideB, long strideC)
{
    __shared__ u16 As[128 * 32];
    __shared__ u16 Bs[128 * 32];

    const int tid = threadIdx.x;
    const int w = tid >> 6;        // wave 0..3
    const int l = tid & 63;        // lane
    const int j0 = blockIdx.x * 128;
    const int i0 = blockIdx.y * 128;

    const u16* Ab = A + (long)blockIdx.z * strideA;
    const u16* Bb = B + (long)blockIdx.z * strideB;

    // staging: per issue, wave w covers 16 rows (lane/4), granule (lane&3)*8 elems
    const int srow = w * 16 + (l >> 2);   // 0..63 (+64 for second issue)
    const int skel = (l & 3) * 8;         // k element offset

    // compute mapping: wave quadrant
    const int i_base = (w >> 1) * 64;
    const int j_base = (w & 1) * 64;
    const int lm = l & 15;
    const int kq = l >> 4;                // 0..3

    floatx4 acc[4][4];
    #pragma unroll
    for (int a = 0; a < 4; ++a)
        #pragma unroll
        for (int b = 0; b < 4; ++b) acc[a][b] = (floatx4)(0.0f);

    for (int k0 = 0; k0 < K; k0 += 32) {
        const u16* ga0 = Ab + (long)(i0 + srow) * ldA + k0 + skel;
        const u16* ga1 = Ab + (long)(i0 + 64 + srow) * ldA + k0 + skel;
        const u16* gb0 = Bb + (long)(j0 + srow) * ldB + k0 + skel;
        const u16* gb1 = Bb + (long)(j0 + 64 + srow) * ldB + k0 + skel;
        char* la0 = (char*)As + w * 1024;
        char* la1 = (char*)As + 4096 + w * 1024;
        char* lb0 = (char*)Bs + w * 1024;
        char* lb1 = (char*)Bs + 4096 + w * 1024;
        __builtin_amdgcn_global_load_lds(
            (const __attribute__((address_space(1))) unsigned int*)(const void*)ga0,
            (__attribute__((address_space(3))) unsigned int*)(void*)la0, 16, 0, 0);
        __builtin_amdgcn_global_load_lds(
            (const __attribute__((address_space(1))) unsigned int*)(const void*)ga1,
            (__attribute__((address_space(3))) unsigned int*)(void*)la1, 16, 0, 0);
        __builtin_amdgcn_global_load_lds(
            (const __attribute__((address_space(1))) unsigned int*)(const void*)gb0,
            (__attribute__((address_space(3))) unsigned int*)(void*)lb0, 16, 0, 0);
        __builtin_amdgcn_global_load_lds(
            (const __attribute__((address_space(1))) unsigned int*)(const void*)gb1,
            (__attribute__((address_space(3))) unsigned int*)(void*)lb1, 16, 0, 0);
        __syncthreads();

        half8 af[4], bf[4];
        #pragma unroll
        for (int t = 0; t < 4; ++t) {
            af[t] = *(const half8*)&As[(i_base + t * 16 + lm) * 32 + kq * 8];
            bf[t] = *(const half8*)&Bs[(j_base + t * 16 + lm) * 32 + kq * 8];
        }
        #pragma unroll
        for (int ti = 0; ti < 4; ++ti)
            #pragma unroll
            for (int tj = 0; tj < 4; ++tj)
                acc[ti][tj] = __builtin_amdgcn_mfma_f32_16x16x32_f16(
                    af[ti], bf[tj], acc[ti][tj], 0, 0, 0);
        __syncthreads();
    }

    OUTT* Cb = C_ + (MODE == 4 ? 0 : (long)blockIdx.z * strideC);
    #pragma unroll
    for (int ti = 0; ti < 4; ++ti) {
        #pragma unroll
        for (int tj = 0; tj < 4; ++tj) {
            const int jj = j0 + j_base + tj * 16 + lm;
            float cinv = 0.f, cbeta = 0.f;
            if (MODE == 1) { cinv = inv_[jj]; cbeta = beta_[jj]; }
            #pragma unroll
            for (int r = 0; r < 4; ++r) {
                const int ii = i0 + i_base + ti * 16 + kq * 4 + r;
                float val = acc[ti][tj][r];
                if (MODE == 1) val = fmaxf(val * cinv + cbeta, 0.0f);
                if (MODE == 2) {
                    float iv = inv_[ii], bt = beta_[ii];
                    val = fmaxf(val * iv + bt, 0.0f);
                }
                if (MODE == 3) val += h2f(addf[(long)ii * ldC + jj]);
                if (MODE == 4) {
                    // strided-pool store of fp32 partial (upper 8KB halves)
                    const long Lb = (((long)blockIdx.z * 4096 + ii) * 512 + jj) * 4;
                    *(float*)((char*)Cb + ((Lb >> 13) << 14) + 8192 + (Lb & 8191)) = val;
                } else if (sizeof(OUTT) == 4) {
                    ((float*)Cb)[(long)ii * ldC + jj] = val;
                } else {
                    ((u16*)Cb)[(long)ii * ldC + jj] = f2h(val);
                }
            }
        }
    }
}

// ---------------------------------------------------------------------------
// split-K reduce: g[n][c] = f[n][c] + sum_{s<4} pool(s,n,c)  (fp16 out)
// pool element (s,n,c): L = (s*2M + n*512 + c)*4 bytes, addr = base +
// ((L>>13)<<14) + 8192 + (L&8191)
// ---------------------------------------------------------------------------
__global__ __launch_bounds__(256)
void reduce_upd(const char* __restrict__ pool, const u16* __restrict__ f,
                u16* __restrict__ g)
{
    const long e = ((long)blockIdx.x * 256 + threadIdx.x) * 4;  // < 2097152
    float4 acc = make_float4(0.f, 0.f, 0.f, 0.f);
    #pragma unroll
    for (int sp = 0; sp < 4; ++sp) {
        const long Lb = (sp * 2097152L + e) * 4;
        const float4 v = *(const float4*)(pool + ((Lb >> 13) << 14) + 8192 + (Lb & 8191));
        acc.x += v.x; acc.y += v.y; acc.z += v.z; acc.w += v.w;
    }
    const uint2 fp = *(const uint2*)&f[e];
    acc.x += h2f((u16)(fp.x & 0xFFFF));
    acc.y += h2f((u16)(fp.x >> 16));
    acc.z += h2f((u16)(fp.y & 0xFFFF));
    acc.w += h2f((u16)(fp.y >> 16));
    uint2 o;
    o.x = (unsigned)f2h(acc.x) | ((unsigned)f2h(acc.y) << 16);
    o.y = (unsigned)f2h(acc.z) | ((unsigned)f2h(acc.w) << 16);
    *(uint2*)&g[e] = o;
}

// ---------------------------------------------------------------------------
// weight fp32 -> fp16 + precompute BN inv/beta
// ---------------------------------------------------------------------------
__global__ __launch_bounds__(256)
void conv_weight(const float* __restrict__ W, const float* __restrict__ g,
                 const float* __restrict__ b, const float* __restrict__ m,
                 const float* __restrict__ v,
                 u16* __restrict__ Wb, float* __restrict__ inv_,
                 float* __restrict__ beta_, int cout, long n)
{
    for (long idx = (long)blockIdx.x * 256 + threadIdx.x; idx < n;
         idx += (long)gridDim.x * 256)
        Wb[idx] = f2h(W[idx]);
    int c = blockIdx.x * 256 + threadIdx.x;
    if (c < cout) {
        float iv = g[c] * rsqrtf(v[c] + EPSV);
        inv_[c] = iv;
        beta_[c] = b[c] - m[c] * iv;
    }
}

// ---------------------------------------------------------------------------
// feature [C][N] fp32 -> featT [N][C] fp16 (32x32 tiled transpose), per batch z
// ---------------------------------------------------------------------------
__global__ __launch_bounds__(256)
void transpose_conv(const float* __restrict__ in, u16* __restrict__ out,
                    int C, int N)
{
    __shared__ float t[32][33];
    const int n0 = blockIdx.x * 32, c0 = blockIdx.y * 32;
    const float* inb = in + (long)blockIdx.z * C * N;
    u16* outb = out + (long)blockIdx.z * C * N;
    const int tx = threadIdx.x & 31, ty = threadIdx.x >> 5;  // 32 x 8
    #pragma unroll
    for (int rr = 0; rr < 32; rr += 8)
        t[ty + rr][tx] = inb[(long)(c0 + ty + rr) * N + n0 + tx];
    __syncthreads();
    #pragma unroll
    for (int rr = 0; rr < 32; rr += 8)
        outb[(long)(n0 + ty + rr) * C + c0 + tx] = f2h(t[tx][ty + rr]);
}

// ---------------------------------------------------------------------------
// Row softmax on S fp32 [4096][4096]; writes fp16 result in-place over the
// first half of each row's own storage (row pitch stays 16384 B -> ld 8192 u16)
// ---------------------------------------------------------------------------
__global__ __launch_bounds__(256)
void softmax_f16(float* __restrict__ S)
{
    __shared__ float buf[4096];
    __shared__ float red[256];
    float* p = S + (long)blockIdx.x * 4096;
    u16* o = (u16*)p;
    const int tid = threadIdx.x;

    float lmax = -3.4e38f;
    for (int i = tid; i < 4096; i += 256) {
        float x = p[i];
        buf[i] = x;
        lmax = fmaxf(lmax, x);
    }
    red[tid] = lmax;
    __syncthreads();
    for (int s = 128; s > 0; s >>= 1) {
        if (tid < s) red[tid] = fmaxf(red[tid], red[tid + s]);
        __syncthreads();
    }
    const float mx = red[0];
    __syncthreads();

    float lsum = 0.0f;
    for (int i = tid; i < 4096; i += 256) {
        float e = __expf(buf[i] - mx);
        buf[i] = e;
        lsum += e;
    }
    red[tid] = lsum;
    __syncthreads();
    for (int s = 128; s > 0; s >>= 1) {
        if (tid < s) red[tid] += red[tid + s];
        __syncthreads();
    }
    const float invs = 1.0f / red[0];
    __syncthreads();

    for (int i = tid; i < 4096; i += 256) o[i] = f2h(buf[i] * invs);
}

// ---------------------------------------------------------------------------
extern "C" void kernel_launch(void* const* d_in, const int* in_sizes, int n_in,
                              void* d_out, int out_size, void* d_ws, size_t ws_size,
                              hipStream_t stream)
{
    (void)in_sizes; (void)n_in; (void)out_size; (void)ws_size;
    constexpr int B = 4, C = 2048, R = 512, N = 4096;
    constexpr long NR = (long)N * R;   // 2,097,152
    constexpr long NC = (long)N * C;   // 8,388,608

    const float* feature = (const float*)d_in[0];
    const float* W_[5]  = {(const float*)d_in[1],  (const float*)d_in[6],
                           (const float*)d_in[11], (const float*)d_in[16],
                           (const float*)d_in[21]};
    const float* G_[5]  = {(const float*)d_in[2],  (const float*)d_in[7],
                           (const float*)d_in[12], (const float*)d_in[17],
                           (const float*)d_in[22]};
    const float* Bb_[5] = {(const float*)d_in[3],  (const float*)d_in[8],
                           (const float*)d_in[13], (const float*)d_in[18],
                           (const float*)d_in[23]};
    const float* M_[5]  = {(const float*)d_in[4],  (const float*)d_in[9],
                           (const float*)d_in[14], (const float*)d_in[19],
                           (const float*)d_in[24]};
    const float* V_[5]  = {(const float*)d_in[5],  (const float*)d_in[10],
                           (const float*)d_in[15], (const float*)d_in[20],
                           (const float*)d_in[25]};
    const int cout_[5] = {R, R, R, R, C};
    const int cin_[5]  = {C, R, R, R, R};

    // ---- workspace layout (bytes) ----
    char* base = (char*)d_ws;
    size_t off = 0;
    // region0: featT fp16 [B][N][C] (64 MB) -- later reused as S fp32 [4096][4096]
    u16*   featT = (u16*)(base + off);
    float* S     = (float*)(base + off);               off += (size_t)B * NC * 2;
    u16* fT = (u16*)(base + off);                      off += (size_t)B * NR * 2;
    u16* qT = (u16*)(base + off);                      off += (size_t)B * NR * 2;
    u16* kT = (u16*)(base + off);                      off += (size_t)B * NR * 2;
    u16* vC = (u16*)(base + off);                      off += (size_t)B * NR * 2;
    u16* gT = (u16*)(base + off);                      off += (size_t)B * NR * 2;
    u16* Wb_[5]; float* inv_[5]; float* beta_[5];
    for (int i = 0; i < 5; ++i) {
        Wb_[i] = (u16*)(base + off);  off += (size_t)cout_[i] * cin_[i] * 2;
        off = (off + 255) & ~(size_t)255;
    }
    for (int i = 0; i < 5; ++i) {
        inv_[i]  = (float*)(base + off);  off += 8192;
        beta_[i] = (float*)(base + off);  off += 8192;
    }

    float* out = (float*)d_out;
    const dim3 blk(256);

    // ---- weight conversion + BN param precompute ----
    for (int i = 0; i < 5; ++i)
        conv_weight<<<512, blk, 0, stream>>>(W_[i], G_[i], Bb_[i], M_[i], V_[i],
                                             Wb_[i], inv_[i], beta_[i],
                                             cout_[i], (long)cout_[i] * cin_[i]);

    // ---- feature transpose+convert: [B][C][N] f32 -> [B][N][C] fp16 ----
    transpose_conv<<<dim3(N / 32, C / 32, B), blk, 0, stream>>>(feature, featT, C, N);

    // ---- f = CBR(feature, r): out fT [B][N][R] fp16 ----
    gemm_nt<1, u16><<<dim3(R / 128, N / 128, B), blk, 0, stream>>>(
        featT, Wb_[0], fT, inv_[0], beta_[0], nullptr,
        C, C, C, R, NC, 0, NR);

    // ---- q,k = CBR(f): [B][N][R] fp16 ----
    gemm_nt<1, u16><<<dim3(R / 128, N / 128, B), blk, 0, stream>>>(
        fT, Wb_[1], qT, inv_[1], beta_[1], nullptr,
        R, R, R, R, NR, 0, NR);
    gemm_nt<1, u16><<<dim3(R / 128, N / 128, B), blk, 0, stream>>>(
        fT, Wb_[2], kT, inv_[2], beta_[2], nullptr,
        R, R, R, R, NR, 0, NR);
    // ---- v = CBR(f), channel-major: vC [B][R][N] fp16 ----
    gemm_nt<2, u16><<<dim3(N / 128, R / 128, B), blk, 0, stream>>>(
        Wb_[3], fT, vC, inv_[3], beta_[3], nullptr,
        R, R, R, N, 0, NR, NR);

    // ---- attention, batch-serial through shared S buffer (aliases featT) ----
    for (int b = 0; b < B; ++b) {
        const u16* qb = qT + (size_t)b * NR;
        const u16* kb = kT + (size_t)b * NR;
        const u16* vb = vC + (size_t)b * NR;
        const u16* fb = fT + (size_t)b * NR;
        u16* gb = gT + (size_t)b * NR;

        // S[i][m] = sum_r q[i][r] * k[m][r]   (fp32)
        gemm_nt<0, float><<<dim3(N / 128, N / 128, 1), blk, 0, stream>>>(
            qb, kb, S, nullptr, nullptr, nullptr,
            R, R, R, N, 0, 0, 0);
        // softmax rows, write fp16 P in place (row pitch 8192 u16);
        // upper 8KB of each 16KB row span becomes the split-K partial pool
        softmax_f16<<<dim3(N), blk, 0, stream>>>(S);
        // split-K upd: partial[s][n][c] = sum_{m in split s} P[n][m]*vC[c][m]
        gemm_nt<4, float><<<dim3(R / 128, N / 128, 4), blk, 0, stream>>>(
            (const u16*)S, vb, S, nullptr, nullptr, nullptr,
            N / 4, 2 * N, N, 0, N / 4, N / 4, 0);
        // g[n][c] = f[n][c] + sum_s partial[s][n][c]
        reduce_upd<<<dim3(2048), blk, 0, stream>>>((const char*)S, fb, gb);
    }

    // ---- out = CBR(f + upd, u): [B][C][N] fp32 ----
    gemm_nt<2, float><<<dim3(N / 128, C / 128, B), blk, 0, stream>>>(
        Wb_[4], gT, out, inv_[4], beta_[4], nullptr,
        R, R, R, N, 0, NR, NC);
}